// Round 1
// baseline (209.925 us; speedup 1.0000x reference)
//
#include <hip/hip_runtime.h>
#include <math.h>

// Problem constants (from reference)
constexpr int L     = 2048;
constexpr int NH    = 96;
constexpr int MLEN  = 150;
constexpr int NAR   = 148;
constexpr float LAM    = 0.001f;
constexpr float CLIP_K = 4.0f;

constexpr int TM     = 16;      // rows per block
constexpr int KM     = 64;      // macro K-tile (2 MFMA sub-steps, split across wave pairs)
constexpr int MSTEPS = L / KM;  // 32

typedef __attribute__((ext_vector_type(8))) short short8;   // 8 bf16 MFMA A/B frag
typedef __attribute__((ext_vector_type(4))) float floatx4;  // MFMA C/D frag

// fp32 -> bf16 round-to-nearest-even
__device__ inline short f2bf(float f) {
    union { float f; unsigned u; } v; v.f = f;
    unsigned r = v.u + 0x7FFFu + ((v.u >> 16) & 1u);
    return (short)(r >> 16);
}

// Pre-kernel: Wt[n][k] = bf16(W[k][n]); 768 KB -> L2-resident gather.
__global__ __launch_bounds__(256) void wt_kernel(
    const float* __restrict__ W, short* __restrict__ Wt)
{
    int idx = blockIdx.x * 256 + threadIdx.x;   // n*2048 + k
    int n = idx >> 11;
    int k = idx & 2047;
    Wt[idx] = f2bf(W[k * NH + n]);
}

// 256 threads = 4 waves per 16-row tile.
// Wave (g,e): g=wv&1 col-half (48 cols), e=wv>>1 k-half (32 of each 64-k step).
// K-halves accumulate independently; one LDS reduction at the end combines them.
// 1024 blocks -> 4 blocks/CU (LDS 39.2 KB), 16 waves/CU for latency hiding.
// A: fp32 staged global->LDS (global_load_lds 16B), double-buffered,
//    16B chunks XOR-swizzled by (row&7) within each 128B half-row.
// B: bf16 Wt staged global->LDS per block per K-tile ([n][k] layout,
//    16B chunks XOR-swizzled by (n&7)).
// MFMA layouts: A[m=lane&15][k=quad*8+j]; B[k=quad*8+j][n=lane&15];
// D col=lane&15, row=quad*4+reg.
__global__ __launch_bounds__(256, 4) void gemm_ar2_kernel(
    const float* __restrict__ x, const short* __restrict__ Wt,
    float* __restrict__ out)
{
    __shared__ float As[2][TM * KM];     // 2 x 4 KB fp32
    __shared__ short Bs[2][NH * KM];     // 2 x 12 KB bf16
    __shared__ float Ys[TM][NH + 1];     // +1 pad (stride-97 writes)
    __shared__ float los[TM], his[TM];
    __shared__ float s2[TM], q2[TM];     // k-half-1 partial stats

    const int t    = threadIdx.x;
    const int lane = t & 63;
    const int wv   = t >> 6;
    const int g    = wv & 1;            // col half
    const int e    = wv >> 1;           // k half (MFMA sub-step this wave owns)
    const int m    = lane & 15;         // local row of this lane's A frag
    const int quad = lane >> 4;
    const int row0 = blockIdx.x * TM;

    // ---- A staging source (1 instr/thread: chunk c = t) ----
    // c -> row = c>>4 (0..15), ch = c&15; within-row: half=ch>>3, pos p=ch&7,
    // source chunk = p ^ (row&7); 16B chunks (4 floats).
    const int rA = t >> 4, chA = t & 15;
    const float* pa = x + (size_t)(row0 + rA) * L
                        + ((chA >> 3) * 32 + ((chA & 7) ^ (rA & 7)) * 4);

    // ---- B staging source (3 instr/wave: chunks c = wv*192 + j*64 + lane) ----
    // c -> n = c>>3, kc = c&7; source chunk = kc ^ (n&7); 16B chunks (8 bf16).
    const int cB0 = wv * 192 + lane, cB1 = cB0 + 64, cB2 = cB0 + 128;
    const short* pb0 = Wt + (size_t)(cB0 >> 3) * L + (((cB0 & 7) ^ ((cB0 >> 3) & 7)) * 8);
    const short* pb1 = Wt + (size_t)(cB1 >> 3) * L + (((cB1 & 7) ^ ((cB1 >> 3) & 7)) * 8);
    const short* pb2 = Wt + (size_t)(cB2 >> 3) * L + (((cB2 & 7) ^ ((cB2 >> 3) & 7)) * 8);

    floatx4 acc[3];
    #pragma unroll
    for (int jj = 0; jj < 3; ++jj) acc[jj] = floatx4{0.f, 0.f, 0.f, 0.f};
    float sum = 0.f, sumsq = 0.f;

    // swizzled A read chunk positions within this wave's k-half (r&7 == m&7)
    const int pA0 = (2 * quad)     ^ (m & 7);
    const int pA1 = (2 * quad + 1) ^ (m & 7);

    auto stage = [&](int buf, int k0) {
        __builtin_amdgcn_global_load_lds(
            (const __attribute__((address_space(1))) unsigned int*)(pa + k0),
            (__attribute__((address_space(3))) unsigned int*)&As[buf][wv * 256], 16, 0, 0);
        __builtin_amdgcn_global_load_lds(
            (const __attribute__((address_space(1))) unsigned int*)(pb0 + k0),
            (__attribute__((address_space(3))) unsigned int*)&Bs[buf][wv * 1536], 16, 0, 0);
        __builtin_amdgcn_global_load_lds(
            (const __attribute__((address_space(1))) unsigned int*)(pb1 + k0),
            (__attribute__((address_space(3))) unsigned int*)&Bs[buf][wv * 1536 + 512], 16, 0, 0);
        __builtin_amdgcn_global_load_lds(
            (const __attribute__((address_space(1))) unsigned int*)(pb2 + k0),
            (__attribute__((address_space(3))) unsigned int*)&Bs[buf][wv * 1536 + 1024], 16, 0, 0);
    };

    stage(0, 0);

    for (int s = 0; s < MSTEPS; ++s) {
        const int cur = s & 1;
        __syncthreads();                       // buf[cur] staged & visible
        if (s + 1 < MSTEPS) stage(cur ^ 1, (s + 1) * KM);

        // this wave's k sub-step ss == e
        float4 f0 = *(const float4*)&As[cur][m * KM + e * 32 + pA0 * 4];
        float4 f1 = *(const float4*)&As[cur][m * KM + e * 32 + pA1 * 4];

        if (g == 0) {   // waves 0,2: each covers its k-half of all 16 rows
            sum  += ((f0.x + f0.y) + (f0.z + f0.w))
                  + ((f1.x + f1.y) + (f1.z + f1.w));
            sumsq = fmaf(f0.x, f0.x, sumsq); sumsq = fmaf(f0.y, f0.y, sumsq);
            sumsq = fmaf(f0.z, f0.z, sumsq); sumsq = fmaf(f0.w, f0.w, sumsq);
            sumsq = fmaf(f1.x, f1.x, sumsq); sumsq = fmaf(f1.y, f1.y, sumsq);
            sumsq = fmaf(f1.z, f1.z, sumsq); sumsq = fmaf(f1.w, f1.w, sumsq);
        }

        short8 af;
        af[0] = f2bf(f0.x); af[1] = f2bf(f0.y); af[2] = f2bf(f0.z); af[3] = f2bf(f0.w);
        af[4] = f2bf(f1.x); af[5] = f2bf(f1.y); af[6] = f2bf(f1.z); af[7] = f2bf(f1.w);

        const int bch = ((e * 4 + quad) ^ (m & 7)) * 8;
        #pragma unroll
        for (int jj = 0; jj < 3; ++jj) {
            short8 bf = *(const short8*)&Bs[cur][(g * 48 + jj * 16 + m) * KM + bch];
            acc[jj] = __builtin_amdgcn_mfma_f32_16x16x32_bf16(af, bf, acc[jj], 0, 0, 0);
        }
    }

    // --- k-half reduction. Reuse Bs[0] (last iter read As[1]/Bs[1]; barrier
    //     at top of s=31 guarantees all waves are past any Bs[0] read). ---
    float* ar = (float*)&Bs[0][0];    // 2 col-halves x 64 lanes x 12 = 6 KB
    if (e == 1) {
        #pragma unroll
        for (int jj = 0; jj < 3; ++jj)
            #pragma unroll
            for (int reg = 0; reg < 4; ++reg)
                ar[(g * 64 + lane) * 12 + jj * 4 + reg] = acc[jj][reg];
        if (g == 0) {   // wave 2: publish k-half-1 stats
            float su = sum, sq = sumsq;
            su += __shfl_xor(su, 16); su += __shfl_xor(su, 32);
            sq += __shfl_xor(sq, 16); sq += __shfl_xor(sq, 32);
            if (quad == 0) { s2[m] = su; q2[m] = sq; }
        }
    }
    __syncthreads();

    if (e == 0) {
        #pragma unroll
        for (int jj = 0; jj < 3; ++jj)
            #pragma unroll
            for (int reg = 0; reg < 4; ++reg)
                acc[jj][reg] += ar[(g * 64 + lane) * 12 + jj * 4 + reg];

        if (g == 0) {   // wave 0: stats + AR2 + clip bounds for all 16 rows
            sum   += __shfl_xor(sum,   16); sum   += __shfl_xor(sum,   32);
            sumsq += __shfl_xor(sumsq, 16); sumsq += __shfl_xor(sumsq, 32);

            const float* ytail = x + (size_t)(row0 + m) * L + (L - MLEN);
            float A11 = 0.f, A22 = 0.f, A12 = 0.f, b1 = 0.f, b2 = 0.f;
            for (int i = quad; i < NAR; i += 4) {
                float p2v = ytail[i];
                float p1v = ytail[i + 1];
                float Yv  = ytail[i + 2];
                A11 = fmaf(p1v, p1v, A11);
                A22 = fmaf(p2v, p2v, A22);
                A12 = fmaf(p1v, p2v, A12);
                b1  = fmaf(p1v, Yv,  b1);
                b2  = fmaf(p2v, Yv,  b2);
            }
            A11 += __shfl_xor(A11, 16); A11 += __shfl_xor(A11, 32);
            A22 += __shfl_xor(A22, 16); A22 += __shfl_xor(A22, 32);
            A12 += __shfl_xor(A12, 16); A12 += __shfl_xor(A12, 32);
            b1  += __shfl_xor(b1,  16); b1  += __shfl_xor(b1,  32);
            b2  += __shfl_xor(b2,  16); b2  += __shfl_xor(b2,  32);

            if (quad == 0) {            // 16 lanes: one row each
                sum   += s2[m];
                sumsq += q2[m];
                A11 += LAM; A22 += LAM;
                float det = A11 * A22 - A12 * A12;
                float a1c = (b1 * A22 - b2 * A12) / det;
                float a2c = (A11 * b2 - A12 * b1) / det;

                float last = ytail[MLEN - 1];
                float y1 = last;
                float y2 = ytail[MLEN - 2];
                for (int n = 0; n < NH; ++n) {
                    float yn = a1c * y1 + a2c * y2;
                    Ys[m][n] = yn;
                    y2 = y1; y1 = yn;
                }
                float var  = (sumsq - sum * sum * (1.0f / L)) * (1.0f / (L - 1));
                float hstd = fmaxf(sqrtf(fmaxf(var, 0.f)), 1e-6f);
                los[m] = last - CLIP_K * hstd;
                his[m] = last + CLIP_K * hstd;
            }
        }
    }
    __syncthreads();

    // --- epilogue: waves 0,1 store the 16x96 tile (wave g: 48-col half) ---
    if (e == 0) {
        #pragma unroll
        for (int reg = 0; reg < 4; ++reg) {
            int rl = quad * 4 + reg;
            float lo = los[rl], hi = his[rl];
            #pragma unroll
            for (int jj = 0; jj < 3; ++jj) {
                int c = (3 * g + jj) * 16 + m;
                float v = acc[jj][reg] + Ys[rl][c];
                v = fminf(fmaxf(v, lo), hi);
                out[(size_t)(row0 + rl) * NH + c] = v;
            }
        }
    }
}

extern "C" void kernel_launch(void* const* d_in, const int* in_sizes, int n_in,
                              void* d_out, int out_size, void* d_ws, size_t ws_size,
                              hipStream_t stream) {
    const float* x = (const float*)d_in[0];   // (32,512,2048) fp32
    const float* W = (const float*)d_in[1];   // (2048,96) fp32
    float* out = (float*)d_out;               // (32,512,96) fp32
    short* Wt  = (short*)d_ws;                // 96*2048 bf16 = 384 KB scratch

    wt_kernel<<<dim3((NH * L) / 256), dim3(256), 0, stream>>>(W, Wt);

    const int rows = 32 * 512;                // 16384
    gemm_ar2_kernel<<<dim3(rows / TM), dim3(256), 0, stream>>>(x, Wt, out);
}